// Round 2
// baseline (231.573 us; speedup 1.0000x reference)
//
#include <hip/hip_runtime.h>

#define B_   4
#define CIN  23
#define H_   256
#define W_   512
#define CO   64

typedef float f32x4 __attribute__((ext_vector_type(4)));

// ---------------------------------------------------------------------------
// Kernel 1: 1x1 conv (23->64) + bias + relu, then mean over H, into avg[B][W][CO].
// Grid: (hsplit=8, wtile=8, B) = 256 blocks, 512 threads (8 waves).
// Lane = w (coalesced), wave = 8-channel group. Weights in LDS (broadcast reads).
// Partial means accumulated with atomicAdd (ws zeroed via hipMemsetAsync).
// ---------------------------------------------------------------------------
__global__ __launch_bounds__(512) void conv_mean_kernel(
    const float* __restrict__ msa,   // [B][CIN][H][W]
    const float* __restrict__ Wc,    // [CO][CIN]
    const float* __restrict__ bias,  // [CO]
    float* __restrict__ avg)         // [B][W][CO]
{
    __shared__ float w_s[CO * CIN];
    __shared__ float b_s[CO];
    const int tid = threadIdx.x;
    for (int idx = tid; idx < CO * CIN; idx += 512) w_s[idx] = Wc[idx];
    if (tid < CO) b_s[tid] = bias[tid];
    __syncthreads();

    const int wl = tid & 63;        // lane within wave = w offset
    const int cg = tid >> 6;        // 0..7 wave id = channel group
    const int c0 = cg * 8;
    const int hs = blockIdx.x;      // 0..7  -> 32 h's each
    const int wt = blockIdx.y;      // 0..7  -> 64 w's each
    const int b  = blockIdx.z;
    const int w  = wt * 64 + wl;
    const int h0 = hs * 32;

    float sum[8];
#pragma unroll
    for (int k = 0; k < 8; ++k) sum[k] = 0.f;

    for (int hb = 0; hb < 32; hb += 4) {
        const int h = h0 + hb;
        float t0[8], t1[8], t2[8], t3[8];
#pragma unroll
        for (int k = 0; k < 8; ++k) {
            const float bb = b_s[c0 + k];
            t0[k] = bb; t1[k] = bb; t2[k] = bb; t3[k] = bb;
        }
        const float* xp = msa + (((size_t)b * CIN) * H_ + h) * W_ + w;
        for (int i = 0; i < CIN; ++i) {
            const float x0 = xp[0];
            const float x1 = xp[W_];
            const float x2 = xp[2 * W_];
            const float x3 = xp[3 * W_];
            xp += (size_t)H_ * W_;
#pragma unroll
            for (int k = 0; k < 8; ++k) {
                const float wk = w_s[(c0 + k) * CIN + i];  // wave-uniform -> LDS broadcast
                t0[k] = fmaf(wk, x0, t0[k]);
                t1[k] = fmaf(wk, x1, t1[k]);
                t2[k] = fmaf(wk, x2, t2[k]);
                t3[k] = fmaf(wk, x3, t3[k]);
            }
        }
#pragma unroll
        for (int k = 0; k < 8; ++k)
            sum[k] += fmaxf(t0[k], 0.f) + fmaxf(t1[k], 0.f) +
                      fmaxf(t2[k], 0.f) + fmaxf(t3[k], 0.f);
    }

    float* dst = avg + ((size_t)(b * W_ + w)) * CO + c0;
#pragma unroll
    for (int k = 0; k < 8; ++k) atomicAdd(dst + k, sum[k] * (1.0f / H_));
}

// ---------------------------------------------------------------------------
// Kernel 2: out[b][wi][wj][c] = avg[b][wi][c] + avg[b][wj][c]
// Grid: (wi=512, b=4), 256 threads: lane layout wj0(4bits high) x cquad(4bits low)
// -> each wave stores 1 KiB contiguous per iteration. avg reads are L1/L2-hot.
// ---------------------------------------------------------------------------
__global__ __launch_bounds__(256) void pairs_kernel(
    const float* __restrict__ avg,  // [B][W][CO]
    float* __restrict__ out)        // [B][W][W][CO]
{
    const int b   = blockIdx.y;
    const int wi  = blockIdx.x;
    const int tid = threadIdx.x;
    const int cq  = tid & 15;   // c-quad (64 c = 16 float4)
    const int wj0 = tid >> 4;   // 0..15

    const f32x4* a4 = (const f32x4*)avg;
    const f32x4 aI = a4[(b * W_ + wi) * 16 + cq];
    f32x4* o4 = (f32x4*)out + ((size_t)(b * W_ + wi)) * W_ * 16;

#pragma unroll 4
    for (int wj = wj0; wj < W_; wj += 16) {
        const f32x4 aJ = a4[(b * W_ + wj) * 16 + cq];
        const f32x4 r = aI + aJ;
        __builtin_nontemporal_store(r, o4 + (size_t)wj * 16 + cq);
    }
}

extern "C" void kernel_launch(void* const* d_in, const int* in_sizes, int n_in,
                              void* d_out, int out_size, void* d_ws, size_t ws_size,
                              hipStream_t stream) {
    const float* msa = (const float*)d_in[0];   // (4, 23, 256, 512)
    const float* Wc  = (const float*)d_in[1];   // (64, 23)
    const float* bc  = (const float*)d_in[2];   // (64,)
    float* out = (float*)d_out;                 // (4, 512, 512, 64)
    float* avg = (float*)d_ws;                  // (4, 512, 64) scratch

    (void)hipMemsetAsync(avg, 0, (size_t)B_ * W_ * CO * sizeof(float), stream);
    conv_mean_kernel<<<dim3(8, 8, B_), 512, 0, stream>>>(msa, Wc, bc, avg);
    pairs_kernel<<<dim3(W_, B_), 256, 0, stream>>>(avg, out);
}

// Round 3
// 113.210 us; speedup vs baseline: 2.0455x; 2.0455x over previous
//
#include <hip/hip_runtime.h>

#define B_   4
#define CIN  23
#define H_   256
#define W_   512
#define CO   64

typedef float f32x4 __attribute__((ext_vector_type(4)));

// ---------------------------------------------------------------------------
// Kernel 1: 1x1 conv (23->64) + bias + relu, mean over H -> avg[B][W][CO].
// Grid: (wq=8, cg=16, b=4) = 512 blocks x 512 threads (8 waves = 4/SIMD).
// Block tile: 64 w (lane = w), 4 channels (c0 = blockIdx.y*4, uniform -> weights
// come from s_load on the scalar pipe; inner loop has ZERO LDS reads).
// Each wave covers 32 h; cross-wave sum via small LDS buffer, no atomics.
// ---------------------------------------------------------------------------
__global__ __launch_bounds__(512) void conv_mean_kernel(
    const float* __restrict__ msa,   // [B][CIN][H][W]
    const float* __restrict__ Wc,    // [CO][CIN]
    const float* __restrict__ bias,  // [CO]
    float* __restrict__ avg)         // [B][W][CO]
{
    const int tid  = threadIdx.x;
    const int lane = tid & 63;
    const int wv   = tid >> 6;            // 0..7 : h-chunk
    const int wq   = blockIdx.x;          // 0..7 : w tile
    const int c0   = blockIdx.y * 4;      // uniform channel group
    const int b    = blockIdx.z;

    const int w  = wq * 64 + lane;
    const int h0 = wv * 32;

    // uniform bias -> SGPRs
    float bs0 = bias[c0 + 0], bs1 = bias[c0 + 1];
    float bs2 = bias[c0 + 2], bs3 = bias[c0 + 3];

    float sum0 = 0.f, sum1 = 0.f, sum2 = 0.f, sum3 = 0.f;

    // base pointer for (b, i=0, h0, w)
    const float* xb = msa + (((size_t)b * CIN) * H_ + h0) * W_ + w;

    for (int hb = 0; hb < 8; ++hb) {       // 4 h per iteration
        float t0[4], t1[4], t2[4], t3[4];  // [hsub] x 4 channels
        t0[0] = bs0; t0[1] = bs1; t0[2] = bs2; t0[3] = bs3;
        t1[0] = bs0; t1[1] = bs1; t1[2] = bs2; t1[3] = bs3;
        t2[0] = bs0; t2[1] = bs1; t2[2] = bs2; t2[3] = bs3;
        t3[0] = bs0; t3[1] = bs1; t3[2] = bs2; t3[3] = bs3;

        const float* xp = xb + hb * 4 * W_;
#pragma unroll
        for (int i = 0; i < CIN; ++i) {
            const float x0 = xp[0];
            const float x1 = xp[W_];
            const float x2 = xp[2 * W_];
            const float x3 = xp[3 * W_];
            xp += (size_t)H_ * W_;
            // uniform weight reads -> s_load, FMA is v_fmac(v, s, v)
            const float wk0 = Wc[(c0 + 0) * CIN + i];
            const float wk1 = Wc[(c0 + 1) * CIN + i];
            const float wk2 = Wc[(c0 + 2) * CIN + i];
            const float wk3 = Wc[(c0 + 3) * CIN + i];
            t0[0] = fmaf(wk0, x0, t0[0]); t0[1] = fmaf(wk1, x0, t0[1]);
            t0[2] = fmaf(wk2, x0, t0[2]); t0[3] = fmaf(wk3, x0, t0[3]);
            t1[0] = fmaf(wk0, x1, t1[0]); t1[1] = fmaf(wk1, x1, t1[1]);
            t1[2] = fmaf(wk2, x1, t1[2]); t1[3] = fmaf(wk3, x1, t1[3]);
            t2[0] = fmaf(wk0, x2, t2[0]); t2[1] = fmaf(wk1, x2, t2[1]);
            t2[2] = fmaf(wk2, x2, t2[2]); t2[3] = fmaf(wk3, x2, t2[3]);
            t3[0] = fmaf(wk0, x3, t3[0]); t3[1] = fmaf(wk1, x3, t3[1]);
            t3[2] = fmaf(wk2, x3, t3[2]); t3[3] = fmaf(wk3, x3, t3[3]);
        }
        sum0 += fmaxf(t0[0], 0.f) + fmaxf(t1[0], 0.f) + fmaxf(t2[0], 0.f) + fmaxf(t3[0], 0.f);
        sum1 += fmaxf(t0[1], 0.f) + fmaxf(t1[1], 0.f) + fmaxf(t2[1], 0.f) + fmaxf(t3[1], 0.f);
        sum2 += fmaxf(t0[2], 0.f) + fmaxf(t1[2], 0.f) + fmaxf(t2[2], 0.f) + fmaxf(t3[2], 0.f);
        sum3 += fmaxf(t0[3], 0.f) + fmaxf(t1[3], 0.f) + fmaxf(t2[3], 0.f) + fmaxf(t3[3], 0.f);
    }

    // cross-wave reduction (8 partial sums per output), no atomics
    __shared__ float red[8][64][4];        // 8 KiB
    red[wv][lane][0] = sum0;
    red[wv][lane][1] = sum1;
    red[wv][lane][2] = sum2;
    red[wv][lane][3] = sum3;
    __syncthreads();

    if (tid < 256) {
        const int l = tid >> 2;            // w-lane
        const int c = tid & 3;             // channel
        float s = 0.f;
#pragma unroll
        for (int k = 0; k < 8; ++k) s += red[k][l][c];
        avg[((size_t)(b * W_ + wq * 64 + l)) * CO + c0 + c] = s * (1.0f / H_);
    }
}

// ---------------------------------------------------------------------------
// Kernel 2: out[b][wi][wj][c] = avg[b][wi][c] + avg[b][wj][c]
// Grid: (wi=512, b=4), 256 threads: each wave stores 1 KiB contiguous per iter.
// avg (512 KB) is L2-resident; output stream uses nontemporal stores.
// ---------------------------------------------------------------------------
__global__ __launch_bounds__(256) void pairs_kernel(
    const float* __restrict__ avg,  // [B][W][CO]
    float* __restrict__ out)        // [B][W][W][CO]
{
    const int b   = blockIdx.y;
    const int wi  = blockIdx.x;
    const int tid = threadIdx.x;
    const int cq  = tid & 15;   // c-quad (64 c = 16 float4)
    const int wj0 = tid >> 4;   // 0..15

    const f32x4* a4 = (const f32x4*)avg;
    const f32x4 aI = a4[(b * W_ + wi) * 16 + cq];
    f32x4* o4 = (f32x4*)out + ((size_t)(b * W_ + wi)) * W_ * 16;

#pragma unroll 4
    for (int wj = wj0; wj < W_; wj += 16) {
        const f32x4 aJ = a4[(b * W_ + wj) * 16 + cq];
        const f32x4 r = aI + aJ;
        __builtin_nontemporal_store(r, o4 + (size_t)wj * 16 + cq);
    }
}

extern "C" void kernel_launch(void* const* d_in, const int* in_sizes, int n_in,
                              void* d_out, int out_size, void* d_ws, size_t ws_size,
                              hipStream_t stream) {
    const float* msa = (const float*)d_in[0];   // (4, 23, 256, 512)
    const float* Wc  = (const float*)d_in[1];   // (64, 23)
    const float* bc  = (const float*)d_in[2];   // (64,)
    float* out = (float*)d_out;                 // (4, 512, 512, 64)
    float* avg = (float*)d_ws;                  // (4, 512, 64) scratch, fully overwritten

    conv_mean_kernel<<<dim3(8, 16, B_), 512, 0, stream>>>(msa, Wc, bc, avg);
    pairs_kernel<<<dim3(W_, B_), 256, 0, stream>>>(avg, out);
}